// Round 6
// baseline (323.290 us; speedup 1.0000x reference)
//
#include <hip/hip_runtime.h>
#include <math.h>

// Problem constants (match reference)
#define BB 8
#define AA 512
#define NBH 64
#define FF 128
#define GG 50
#define CUTOFF 5.0f

typedef __attribute__((ext_vector_type(8)))  short bf16x8;   // 8 bf16 = 4 VGPRs
typedef __attribute__((ext_vector_type(4)))  float f32x4;    // 16x16 MFMA C/D
typedef __attribute__((ext_vector_type(16))) float f32x16;   // 32x32 MFMA C/D

#define MST 136   // M_s row stride (shorts); with XOR swizzle reads/writes are conflict-light

// Packed weight sizes (bf16 elems)
#define WKV_ELEMS (4*8*64*8)   // 16384 : Wk/Wv, 32-col B-frag layout, K=128 (8 steps of 16)
#define WQO_ELEMS (8*4*64*8)   // 16384 : Wq/Wo, 16-col B-frag layout, K=128 (4 steps of 32)
#define WF_ELEMS  (4*4*64*8)   // 8192  : W_filt, 32-col layout, K=64 pad (4 steps of 16)

__device__ __forceinline__ short f2bf(float f) {
    union { float f; unsigned u; } v; v.f = f;
    unsigned r = v.u + 0x7fffu + ((v.u >> 16) & 1u);   // RNE
    return (short)(r >> 16);
}

__device__ __forceinline__ int swz(int n) { return ((n >> 3) & 3) << 3; }  // LDS k-index XOR swizzle

// Load 8 consecutive floats (8B-aligned) from global, convert to a bf16x8 A-fragment.
__device__ __forceinline__ bf16x8 ld_f8_bf(const float* p) {
    const float2* p2 = (const float2*)p;
    float2 a = p2[0], b = p2[1], c = p2[2], d = p2[3];
    bf16x8 r;
    r[0] = f2bf(a.x); r[1] = f2bf(a.y); r[2] = f2bf(b.x); r[3] = f2bf(b.y);
    r[4] = f2bf(c.x); r[5] = f2bf(c.y); r[6] = f2bf(d.x); r[7] = f2bf(d.y);
    return r;
}

// Sum over the 16-lane DPP row (VALU pipe, no DS traffic). All 16 lanes get the sum.
__device__ __forceinline__ float row16_sum(float x) {
    int t;
    t = __builtin_amdgcn_update_dpp(0, __float_as_int(x), 0x128, 0xf, 0xf, true); x += __int_as_float(t); // row_ror:8
    t = __builtin_amdgcn_update_dpp(0, __float_as_int(x), 0x124, 0xf, 0xf, true); x += __int_as_float(t); // row_ror:4
    t = __builtin_amdgcn_update_dpp(0, __float_as_int(x), 0x122, 0xf, 0xf, true); x += __int_as_float(t); // row_ror:2
    t = __builtin_amdgcn_update_dpp(0, __float_as_int(x), 0x121, 0xf, 0xf, true); x += __int_as_float(t); // row_ror:1
    return x;
}

// ---------------- prep: pack weights into MFMA B-fragment order ----------------
// 32-col layout (Wk/Wv/Wf): dst[((w*S+s)*64+l)*8+j] = W[16s + (l>>5)*8 + j][32w + (l&31)]
// 16-col layout (Wq/Wo):    dst[((c*4+s)*64+l)*8+j] = W[32s + (l>>4)*8 + j][16c + (l&15)]
__global__ void prep_kernel(const float* __restrict__ Wk,
                            const float* __restrict__ Wv,
                            const float* __restrict__ Wq,
                            const float* __restrict__ Wo,
                            const float* __restrict__ Wf,
                            short* __restrict__ ws)
{
    int gid = blockIdx.x * blockDim.x + threadIdx.x;
    if (gid < 2 * WKV_ELEMS) {
        const float* src = (gid < WKV_ELEMS) ? Wk : Wv;
        int idx = gid & (WKV_ELEMS - 1);
        int j = idx & 7, l = (idx >> 3) & 63, rest = idx >> 9;
        int s = rest & 7, w = rest >> 3;
        int k = 16 * s + ((l >> 5) << 3) + j;
        int n = 32 * w + (l & 31);
        ws[gid] = f2bf(src[k * FF + n]);
    } else if (gid < 2 * WKV_ELEMS + 2 * WQO_ELEMS) {
        int idx2 = gid - 2 * WKV_ELEMS;
        const float* src = (idx2 < WQO_ELEMS) ? Wq : Wo;
        int idx = idx2 & (WQO_ELEMS - 1);
        int j = idx & 7, l = (idx >> 3) & 63, rest = idx >> 9;
        int s = rest & 3, c = rest >> 2;
        int k = 32 * s + (l >> 4) * 8 + j;
        int n = 16 * c + (l & 15);
        ws[gid] = f2bf(src[k * FF + n]);
    } else {
        int idx = gid - 2 * WKV_ELEMS - 2 * WQO_ELEMS;
        int j = idx & 7, l = (idx >> 3) & 63, rest = idx >> 9;
        int s = rest & 3, w = rest >> 2;
        int k = 16 * s + ((l >> 5) << 3) + j;
        int n = 32 * w + (l & 31);
        ws[gid] = (k < GG) ? f2bf(Wf[k * FF + n]) : (short)0;
    }
}

// ---------------- main: one block per atom, 4 waves, 2 barriers ----------------
// Wave w owns cols [32w, 32w+32) == heads {2w, 2w+1}, all 64 neighbors.
// 32x32x16 layouts: A[m=lane&31][k=(lane>>5)*8+j]  B[k][n=lane&31]
//                   D: col=lane&31, row=(reg&3)+8*(reg>>2)+4*(lane>>5)
// 16x16x32 (broadcast-A matvecs): A[m=lane&15][k=(lane>>4)*8+j], D col=lane&15.
__global__ __launch_bounds__(256, 6)
void tdt_main(const float* __restrict__ x,
              const float* __restrict__ r_ij,
              const float* __restrict__ f_ij,
              const float* __restrict__ b_filt,
              const float* __restrict__ bo,
              const int*   __restrict__ neighbors,
              const int*   __restrict__ nmask,
              const short* __restrict__ WkB,
              const short* __restrict__ WvB,
              const short* __restrict__ WqB,
              const short* __restrict__ WoB,
              const short* __restrict__ WfB,
              float* __restrict__ out)
{
    const int ba   = blockIdx.x;          // 0..4095
    const int b    = ba >> 9;
    const int tid  = threadIdx.x;
    const int lane = tid & 63;
    const int w    = tid >> 6;            // wave 0..3
    const int l15  = lane & 15;
    const int quad = lane >> 4;
    const int l31  = lane & 31;
    const int khalf = (lane >> 5) << 3;   // 0 or 8
    const int w5_4  = (lane >> 5) * 4;

    __shared__ short M_s[NBH * MST];      // modulated messages, swizzled (17.4 KB)
    __shared__ short msg_bf[FF];

    const float* xrow = x + (size_t)ba * FF;   // this atom's features
    const float* xb   = x + (size_t)b * AA * FF;
    const size_t bao  = (size_t)ba;

    // per-lane neighbor metadata in REGISTERS (no LDS, no barrier):
    int   nbr_reg = neighbors[bao * NBH + lane];
    float C_reg;
    {
        float r = r_ij[bao * NBH + lane];
        float c = 0.5f * (__cosf((float)M_PI * r * (1.0f / CUTOFF)) + 1.0f);
        C_reg = (r < CUTOFF) ? c : 0.0f;
    }
    unsigned long long mask64 = __ballot(nmask[bao * NBH + lane] != 0);

    // ---------------- phase 1a: q via 16x16x32 MFMA (broadcast-A from global x) -----
    float qv[2];
    {
#pragma unroll
        for (int ct = 0; ct < 2; ++ct) {
            int cg = 2 * w + ct;
            f32x4 z = {0.f, 0.f, 0.f, 0.f};
#pragma unroll
            for (int s = 0; s < 4; ++s) {
                bf16x8 xa = ld_f8_bf(xrow + 32 * s + quad * 8);
                bf16x8 bq = *(const bf16x8*)&WqB[((cg * 4 + s) * 64 + lane) * 8];
                z = __builtin_amdgcn_mfma_f32_16x16x32_bf16(xa, bq, z, 0, 0, 0);
            }
            qv[ct] = z[0];   // all rows identical; col = cg*16 + l15
        }
    }

    // ---------------- phase 1b: filter 32x32x16 MFMA (A from global f_ij) -----------
    {
        f32x16 wacc[2];
#pragma unroll
        for (int mt = 0; mt < 2; ++mt)
#pragma unroll
            for (int r = 0; r < 16; ++r) wacc[mt][r] = 0.0f;

        const float* fm0 = f_ij + bao * (size_t)(NBH * GG) + (size_t)l31 * GG;
#pragma unroll
        for (int s = 0; s < 4; ++s) {
            bf16x8 bfw = *(const bf16x8*)&WfB[((w * 4 + s) * 64 + lane) * 8];
#pragma unroll
            for (int mt = 0; mt < 2; ++mt) {
                const float* fm = fm0 + mt * 32 * GG;
                bf16x8 fa;
                if (s < 3) {
                    fa = ld_f8_bf(fm + 16 * s + khalf);
                } else {
                    // k = 48 + khalf + j; valid only k<50 -> lower half j=0,1
#pragma unroll
                    for (int jj = 0; jj < 8; ++jj) fa[jj] = 0;
                    if (lane < 32) { fa[0] = f2bf(fm[48]); fa[1] = f2bf(fm[49]); }
                }
                wacc[mt] = __builtin_amdgcn_mfma_f32_32x32x16_bf16(fa, bfw, wacc[mt], 0, 0, 0);
            }
        }

        // modulate + gather + write M_s (neighbor meta via register shuffles)
        int   c    = 32 * w + l31;
        float bflt = b_filt[c];
#pragma unroll
        for (int mt = 0; mt < 2; ++mt) {
#pragma unroll
            for (int r = 0; r < 16; ++r) {
                int   n   = 32 * mt + (r & 3) + 8 * (r >> 2) + w5_4;
                int   nbn = __shfl(nbr_reg, n, 64);
                float cn  = __shfl(C_reg, n, 64);
                float xv  = xb[(size_t)nbn * FF + c];   // 128B segments, coalesced
                M_s[n * MST + (c ^ swz(n))] = f2bf((wacc[mt][r] + bflt) * cn * xv);
            }
        }
    }
    __syncthreads();   // M_s ready

    // ---------------- phase 2a: k via 32x32x16 MFMA -> scores (DPP) -> softmax ------
    float sc[2][16];
    float inv;
    {
        f32x16 kacc[2];
#pragma unroll
        for (int mt = 0; mt < 2; ++mt)
#pragma unroll
            for (int r = 0; r < 16; ++r) kacc[mt][r] = 0.0f;
#pragma unroll
        for (int s = 0; s < 8; ++s) {
            bf16x8 bk = *(const bf16x8*)&WkB[((w * 8 + s) * 64 + lane) * 8];
            int kb = 16 * s + khalf;
#pragma unroll
            for (int mt = 0; mt < 2; ++mt) {
                int m = 32 * mt + l31;
                bf16x8 ma = *(const bf16x8*)&M_s[m * MST + (kb ^ swz(m))];
                kacc[mt] = __builtin_amdgcn_mfma_f32_32x32x16_bf16(ma, bk, kacc[mt], 0, 0, 0);
            }
        }
        float qvm = qv[(lane >> 4) & 1];          // q[32w + (lane&31)]
#pragma unroll
        for (int mt = 0; mt < 2; ++mt) {
#pragma unroll
            for (int r = 0; r < 16; ++r) {
                float s = row16_sum(kacc[mt][r] * qvm) * 0.25f;   // 1/sqrt(DH)
                int n = 32 * mt + (r & 3) + 8 * (r >> 2) + w5_4;
                sc[mt][r] = ((mask64 >> n) & 1ull) ? s : -1e9f;
            }
        }
        float mx = -1e30f;
#pragma unroll
        for (int mt = 0; mt < 2; ++mt)
#pragma unroll
            for (int r = 0; r < 16; ++r) mx = fmaxf(mx, sc[mt][r]);
        mx = fmaxf(mx, __shfl_xor(mx, 32, 64));
        float sum = 0.0f;
#pragma unroll
        for (int mt = 0; mt < 2; ++mt)
#pragma unroll
            for (int r = 0; r < 16; ++r) {
                float e = __expf(sc[mt][r] - mx);
                sc[mt][r] = e;
                sum += e;
            }
        sum += __shfl_xor(sum, 32, 64);
        inv = 1.0f / sum;
    }

    // ---------------- phase 2b: v MFMA fused into msg (one mt tile live at a time) --
    {
        float acc = 0.0f;
#pragma unroll
        for (int mt = 0; mt < 2; ++mt) {
            f32x16 vacc;
#pragma unroll
            for (int r = 0; r < 16; ++r) vacc[r] = 0.0f;
            int m = 32 * mt + l31;
#pragma unroll
            for (int s = 0; s < 8; ++s) {
                bf16x8 bv = *(const bf16x8*)&WvB[((w * 8 + s) * 64 + lane) * 8];
                int kb = 16 * s + khalf;
                bf16x8 ma = *(const bf16x8*)&M_s[m * MST + (kb ^ swz(m))];
                vacc = __builtin_amdgcn_mfma_f32_32x32x16_bf16(ma, bv, vacc, 0, 0, 0);
            }
#pragma unroll
            for (int r = 0; r < 16; ++r)
                acc = fmaf(sc[mt][r], vacc[r], acc);
        }
        acc += __shfl_xor(acc, 32, 64);
        if (lane < 32) msg_bf[32 * w + l31] = f2bf(acc * inv);
    }
    __syncthreads();   // msg_bf ready

    // ---------------- phase 3: out = msg.Wo + x + bo (16x16x32, broadcast-A) --------
    {
        bf16x8 mga[4];
#pragma unroll
        for (int s = 0; s < 4; ++s)
            mga[s] = *(const bf16x8*)&msg_bf[s * 32 + quad * 8];
#pragma unroll
        for (int ct = 0; ct < 2; ++ct) {
            int cg = 2 * w + ct;
            f32x4 z = {0.f, 0.f, 0.f, 0.f};
#pragma unroll
            for (int s = 0; s < 4; ++s) {
                bf16x8 bw = *(const bf16x8*)&WoB[((cg * 4 + s) * 64 + lane) * 8];
                z = __builtin_amdgcn_mfma_f32_16x16x32_bf16(mga[s], bw, z, 0, 0, 0);
            }
            if (quad == 0) {
                int col = cg * 16 + l15;
                out[bao * FF + col] = z[0] + xrow[col] + bo[col];
            }
        }
    }
}

extern "C" void kernel_launch(void* const* d_in, const int* in_sizes, int n_in,
                              void* d_out, int out_size, void* d_ws, size_t ws_size,
                              hipStream_t stream) {
    // 0:e 1:x 2:t 3:r_ij 4:f_ij 5:W_filt 6:b_filt 7:Wq 8:Wk 9:Wv 10:Wo 11:bo
    // 12:neighbors 13:neighbor_mask (bool -> int32)
    const float* x      = (const float*)d_in[1];
    const float* r_ij   = (const float*)d_in[3];
    const float* f_ij   = (const float*)d_in[4];
    const float* W_filt = (const float*)d_in[5];
    const float* b_filt = (const float*)d_in[6];
    const float* Wq     = (const float*)d_in[7];
    const float* Wk     = (const float*)d_in[8];
    const float* Wv     = (const float*)d_in[9];
    const float* Wo     = (const float*)d_in[10];
    const float* bo     = (const float*)d_in[11];
    const int*   nbr    = (const int*)d_in[12];
    const int*   msk    = (const int*)d_in[13];
    float* out = (float*)d_out;

    short* ws  = (short*)d_ws;   // 73728 bf16 = 144 KB scratch
    short* WkB = ws;
    short* WvB = ws + WKV_ELEMS;
    short* WqB = ws + 2 * WKV_ELEMS;
    short* WoB = ws + 2 * WKV_ELEMS + WQO_ELEMS;
    short* WfB = ws + 2 * WKV_ELEMS + 2 * WQO_ELEMS;

    int prep_total = 2 * WKV_ELEMS + 2 * WQO_ELEMS + WF_ELEMS;   // 73728 = 288 * 256
    hipLaunchKernelGGL(prep_kernel, dim3(prep_total / 256), dim3(256), 0, stream,
                       Wk, Wv, Wq, Wo, W_filt, ws);
    hipLaunchKernelGGL(tdt_main, dim3(BB * AA), dim3(256), 0, stream,
                       x, r_ij, f_ij, b_filt, bo, nbr, msk,
                       WkB, WvB, WqB, WoB, WfB, out);
}

// Round 7
// 164.016 us; speedup vs baseline: 1.9711x; 1.9711x over previous
//
#include <hip/hip_runtime.h>
#include <math.h>

// Problem constants (match reference)
#define BB 8
#define AA 512
#define NBH 64
#define FF 128
#define GG 50
#define CUTOFF 5.0f

typedef __attribute__((ext_vector_type(8)))  short bf16x8;   // 8 bf16 = 4 VGPRs
typedef __attribute__((ext_vector_type(4)))  float f32x4;    // 16x16 MFMA C/D
typedef __attribute__((ext_vector_type(16))) float f32x16;   // 32x32 MFMA C/D

#define MST 136   // M_s row stride (shorts); with XOR swizzle reads/writes are conflict-light

// Packed weight sizes (bf16 elems)
#define WKV_ELEMS (4*8*64*8)   // 16384 : Wk/Wv, 32-col B-frag layout, K=128 (8 steps of 16)
#define WQO_ELEMS (8*4*64*8)   // 16384 : Wq/Wo, 16-col B-frag layout, K=128 (4 steps of 32)
#define WF_ELEMS  (4*4*64*8)   // 8192  : W_filt, 32-col layout, K=64 pad (4 steps of 16)

__device__ __forceinline__ short f2bf(float f) {
    union { float f; unsigned u; } v; v.f = f;
    unsigned r = v.u + 0x7fffu + ((v.u >> 16) & 1u);   // RNE
    return (short)(r >> 16);
}

__device__ __forceinline__ int swz(int n) { return ((n >> 3) & 3) << 3; }  // LDS k-index XOR swizzle

// Load 8 consecutive floats (8B-aligned) from global, convert to a bf16x8 A-fragment.
__device__ __forceinline__ bf16x8 ld_f8_bf(const float* p) {
    const float2* p2 = (const float2*)p;
    float2 a = p2[0], b = p2[1], c = p2[2], d = p2[3];
    bf16x8 r;
    r[0] = f2bf(a.x); r[1] = f2bf(a.y); r[2] = f2bf(b.x); r[3] = f2bf(b.y);
    r[4] = f2bf(c.x); r[5] = f2bf(c.y); r[6] = f2bf(d.x); r[7] = f2bf(d.y);
    return r;
}

// Sum over the 16-lane DPP row (VALU pipe, no DS traffic). All 16 lanes get the sum.
__device__ __forceinline__ float row16_sum(float x) {
    int t;
    t = __builtin_amdgcn_update_dpp(0, __float_as_int(x), 0x128, 0xf, 0xf, true); x += __int_as_float(t); // row_ror:8
    t = __builtin_amdgcn_update_dpp(0, __float_as_int(x), 0x124, 0xf, 0xf, true); x += __int_as_float(t); // row_ror:4
    t = __builtin_amdgcn_update_dpp(0, __float_as_int(x), 0x122, 0xf, 0xf, true); x += __int_as_float(t); // row_ror:2
    t = __builtin_amdgcn_update_dpp(0, __float_as_int(x), 0x121, 0xf, 0xf, true); x += __int_as_float(t); // row_ror:1
    return x;
}

// ---------------- prep: pack weights into MFMA B-fragment order ----------------
// 32-col layout (Wk/Wv/Wf): dst[((w*S+s)*64+l)*8+j] = W[16s + (l>>5)*8 + j][32w + (l&31)]
// 16-col layout (Wq/Wo):    dst[((c*4+s)*64+l)*8+j] = W[32s + (l>>4)*8 + j][16c + (l&15)]
__global__ void prep_kernel(const float* __restrict__ Wk,
                            const float* __restrict__ Wv,
                            const float* __restrict__ Wq,
                            const float* __restrict__ Wo,
                            const float* __restrict__ Wf,
                            short* __restrict__ ws)
{
    int gid = blockIdx.x * blockDim.x + threadIdx.x;
    if (gid < 2 * WKV_ELEMS) {
        const float* src = (gid < WKV_ELEMS) ? Wk : Wv;
        int idx = gid & (WKV_ELEMS - 1);
        int j = idx & 7, l = (idx >> 3) & 63, rest = idx >> 9;
        int s = rest & 7, w = rest >> 3;
        int k = 16 * s + ((l >> 5) << 3) + j;
        int n = 32 * w + (l & 31);
        ws[gid] = f2bf(src[k * FF + n]);
    } else if (gid < 2 * WKV_ELEMS + 2 * WQO_ELEMS) {
        int idx2 = gid - 2 * WKV_ELEMS;
        const float* src = (idx2 < WQO_ELEMS) ? Wq : Wo;
        int idx = idx2 & (WQO_ELEMS - 1);
        int j = idx & 7, l = (idx >> 3) & 63, rest = idx >> 9;
        int s = rest & 3, c = rest >> 2;
        int k = 32 * s + (l >> 4) * 8 + j;
        int n = 16 * c + (l & 15);
        ws[gid] = f2bf(src[k * FF + n]);
    } else {
        int idx = gid - 2 * WKV_ELEMS - 2 * WQO_ELEMS;
        int j = idx & 7, l = (idx >> 3) & 63, rest = idx >> 9;
        int s = rest & 3, w = rest >> 2;
        int k = 16 * s + ((l >> 5) << 3) + j;
        int n = 32 * w + (l & 31);
        ws[gid] = (k < GG) ? f2bf(Wf[k * FF + n]) : (short)0;
    }
}

// ---------------- main: one block per atom, 4 waves, 2 barriers ----------------
// Wave w owns cols [32w, 32w+32) == heads {2w, 2w+1}, all 64 neighbors.
// 32x32x16 layouts: A[m=lane&31][k=(lane>>5)*8+j]  B[k][n=lane&31]
//                   D: col=lane&31, row=(reg&3)+8*(reg>>2)+4*(lane>>5)
// 16x16x32 (broadcast-A matvecs): A[m=lane&15][k=(lane>>4)*8+j], D col=lane&15.
// launch_bounds min-waves=4 (128-reg cap): 6 forced catastrophic scratch spill
// (R6: WRITE_SIZE 405 MB). Peak live-set ~100 regs; allocator may still reach
// 5 waves naturally if it lands <=102.
__global__ __launch_bounds__(256, 4)
void tdt_main(const float* __restrict__ x,
              const float* __restrict__ r_ij,
              const float* __restrict__ f_ij,
              const float* __restrict__ b_filt,
              const float* __restrict__ bo,
              const int*   __restrict__ neighbors,
              const int*   __restrict__ nmask,
              const short* __restrict__ WkB,
              const short* __restrict__ WvB,
              const short* __restrict__ WqB,
              const short* __restrict__ WoB,
              const short* __restrict__ WfB,
              float* __restrict__ out)
{
    const int ba   = blockIdx.x;          // 0..4095
    const int b    = ba >> 9;
    const int tid  = threadIdx.x;
    const int lane = tid & 63;
    const int w    = tid >> 6;            // wave 0..3
    const int l15  = lane & 15;
    const int quad = lane >> 4;
    const int l31  = lane & 31;
    const int khalf = (lane >> 5) << 3;   // 0 or 8
    const int w5_4  = (lane >> 5) * 4;

    __shared__ short M_s[NBH * MST];      // modulated messages, swizzled (17.4 KB)
    __shared__ short msg_bf[FF];

    const float* xrow = x + (size_t)ba * FF;   // this atom's features
    const float* xb   = x + (size_t)b * AA * FF;
    const size_t bao  = (size_t)ba;

    // per-lane neighbor metadata in REGISTERS (no LDS, no barrier):
    int   nbr_reg = neighbors[bao * NBH + lane];
    float C_reg;
    {
        float r = r_ij[bao * NBH + lane];
        float c = 0.5f * (__cosf((float)M_PI * r * (1.0f / CUTOFF)) + 1.0f);
        C_reg = (r < CUTOFF) ? c : 0.0f;
    }
    unsigned long long mask64 = __ballot(nmask[bao * NBH + lane] != 0);

    // ---------------- phase 1a: q via 16x16x32 MFMA (broadcast-A from global x) -----
    // Only qvm = q[32w + (lane&31)] is kept live downstream (1 reg, not 2).
    float qvm;
    {
        float qv0, qv1;
#pragma unroll
        for (int ct = 0; ct < 2; ++ct) {
            int cg = 2 * w + ct;
            f32x4 z = {0.f, 0.f, 0.f, 0.f};
#pragma unroll
            for (int s = 0; s < 4; ++s) {
                bf16x8 xa = ld_f8_bf(xrow + 32 * s + quad * 8);
                bf16x8 bq = *(const bf16x8*)&WqB[((cg * 4 + s) * 64 + lane) * 8];
                z = __builtin_amdgcn_mfma_f32_16x16x32_bf16(xa, bq, z, 0, 0, 0);
            }
            if (ct == 0) qv0 = z[0]; else qv1 = z[0];
        }
        qvm = ((lane >> 4) & 1) ? qv1 : qv0;
    }

    // ---------------- phase 1b: filter 32x32x16 MFMA (A from global f_ij) -----------
    {
        f32x16 wacc[2];
#pragma unroll
        for (int mt = 0; mt < 2; ++mt)
#pragma unroll
            for (int r = 0; r < 16; ++r) wacc[mt][r] = 0.0f;

        const float* fm0 = f_ij + bao * (size_t)(NBH * GG) + (size_t)l31 * GG;
#pragma unroll
        for (int s = 0; s < 4; ++s) {
            bf16x8 bfw = *(const bf16x8*)&WfB[((w * 4 + s) * 64 + lane) * 8];
#pragma unroll
            for (int mt = 0; mt < 2; ++mt) {
                const float* fm = fm0 + mt * 32 * GG;
                bf16x8 fa;
                if (s < 3) {
                    fa = ld_f8_bf(fm + 16 * s + khalf);
                } else {
                    // k = 48 + khalf + j; valid only k<50 -> lower half j=0,1
#pragma unroll
                    for (int jj = 0; jj < 8; ++jj) fa[jj] = 0;
                    if (lane < 32) { fa[0] = f2bf(fm[48]); fa[1] = f2bf(fm[49]); }
                }
                wacc[mt] = __builtin_amdgcn_mfma_f32_32x32x16_bf16(fa, bfw, wacc[mt], 0, 0, 0);
            }
        }

        // modulate + gather + write M_s (neighbor meta via register shuffles)
        int   c    = 32 * w + l31;
        float bflt = b_filt[c];
#pragma unroll
        for (int mt = 0; mt < 2; ++mt) {
#pragma unroll
            for (int r = 0; r < 16; ++r) {
                int   n   = 32 * mt + (r & 3) + 8 * (r >> 2) + w5_4;
                int   nbn = __shfl(nbr_reg, n, 64);
                float cn  = __shfl(C_reg, n, 64);
                float xv  = xb[(size_t)nbn * FF + c];   // 128B segments, coalesced
                M_s[n * MST + (c ^ swz(n))] = f2bf((wacc[mt][r] + bflt) * cn * xv);
            }
        }
    }
    __syncthreads();   // M_s ready

    // ---------------- phase 2a: k via 32x32x16 MFMA -> scores (DPP) -> softmax ------
    float sc[2][16];
    float inv;
    {
        f32x16 kacc[2];
#pragma unroll
        for (int mt = 0; mt < 2; ++mt)
#pragma unroll
            for (int r = 0; r < 16; ++r) kacc[mt][r] = 0.0f;
#pragma unroll
        for (int s = 0; s < 8; ++s) {
            bf16x8 bk = *(const bf16x8*)&WkB[((w * 8 + s) * 64 + lane) * 8];
            int kb = 16 * s + khalf;
#pragma unroll
            for (int mt = 0; mt < 2; ++mt) {
                int m = 32 * mt + l31;
                bf16x8 ma = *(const bf16x8*)&M_s[m * MST + (kb ^ swz(m))];
                kacc[mt] = __builtin_amdgcn_mfma_f32_32x32x16_bf16(ma, bk, kacc[mt], 0, 0, 0);
            }
        }
#pragma unroll
        for (int mt = 0; mt < 2; ++mt) {
#pragma unroll
            for (int r = 0; r < 16; ++r) {
                float s = row16_sum(kacc[mt][r] * qvm) * 0.25f;   // 1/sqrt(DH)
                int n = 32 * mt + (r & 3) + 8 * (r >> 2) + w5_4;
                sc[mt][r] = ((mask64 >> n) & 1ull) ? s : -1e9f;
            }
        }
        float mx = -1e30f;
#pragma unroll
        for (int mt = 0; mt < 2; ++mt)
#pragma unroll
            for (int r = 0; r < 16; ++r) mx = fmaxf(mx, sc[mt][r]);
        mx = fmaxf(mx, __shfl_xor(mx, 32, 64));
        float sum = 0.0f;
#pragma unroll
        for (int mt = 0; mt < 2; ++mt)
#pragma unroll
            for (int r = 0; r < 16; ++r) {
                float e = __expf(sc[mt][r] - mx);
                sc[mt][r] = e;
                sum += e;
            }
        sum += __shfl_xor(sum, 32, 64);
        inv = 1.0f / sum;
    }

    // ---------------- phase 2b: v MFMA fused into msg (one mt tile live at a time) --
    {
        float acc = 0.0f;
#pragma unroll
        for (int mt = 0; mt < 2; ++mt) {
            f32x16 vacc;
#pragma unroll
            for (int r = 0; r < 16; ++r) vacc[r] = 0.0f;
            int m = 32 * mt + l31;
#pragma unroll
            for (int s = 0; s < 8; ++s) {
                bf16x8 bv = *(const bf16x8*)&WvB[((w * 8 + s) * 64 + lane) * 8];
                int kb = 16 * s + khalf;
                bf16x8 ma = *(const bf16x8*)&M_s[m * MST + (kb ^ swz(m))];
                vacc = __builtin_amdgcn_mfma_f32_32x32x16_bf16(ma, bv, vacc, 0, 0, 0);
            }
#pragma unroll
            for (int r = 0; r < 16; ++r)
                acc = fmaf(sc[mt][r], vacc[r], acc);
        }
        acc += __shfl_xor(acc, 32, 64);
        if (lane < 32) msg_bf[32 * w + l31] = f2bf(acc * inv);
    }
    __syncthreads();   // msg_bf ready

    // ---------------- phase 3: out = msg.Wo + x + bo (16x16x32, broadcast-A) --------
    {
        bf16x8 mga[4];
#pragma unroll
        for (int s = 0; s < 4; ++s)
            mga[s] = *(const bf16x8*)&msg_bf[s * 32 + quad * 8];
#pragma unroll
        for (int ct = 0; ct < 2; ++ct) {
            int cg = 2 * w + ct;
            f32x4 z = {0.f, 0.f, 0.f, 0.f};
#pragma unroll
            for (int s = 0; s < 4; ++s) {
                bf16x8 bw = *(const bf16x8*)&WoB[((cg * 4 + s) * 64 + lane) * 8];
                z = __builtin_amdgcn_mfma_f32_16x16x32_bf16(mga[s], bw, z, 0, 0, 0);
            }
            if (quad == 0) {
                int col = cg * 16 + l15;
                out[bao * FF + col] = z[0] + xrow[col] + bo[col];
            }
        }
    }
}

extern "C" void kernel_launch(void* const* d_in, const int* in_sizes, int n_in,
                              void* d_out, int out_size, void* d_ws, size_t ws_size,
                              hipStream_t stream) {
    // 0:e 1:x 2:t 3:r_ij 4:f_ij 5:W_filt 6:b_filt 7:Wq 8:Wk 9:Wv 10:Wo 11:bo
    // 12:neighbors 13:neighbor_mask (bool -> int32)
    const float* x      = (const float*)d_in[1];
    const float* r_ij   = (const float*)d_in[3];
    const float* f_ij   = (const float*)d_in[4];
    const float* W_filt = (const float*)d_in[5];
    const float* b_filt = (const float*)d_in[6];
    const float* Wq     = (const float*)d_in[7];
    const float* Wk     = (const float*)d_in[8];
    const float* Wv     = (const float*)d_in[9];
    const float* Wo     = (const float*)d_in[10];
    const float* bo     = (const float*)d_in[11];
    const int*   nbr    = (const int*)d_in[12];
    const int*   msk    = (const int*)d_in[13];
    float* out = (float*)d_out;

    short* ws  = (short*)d_ws;   // 73728 bf16 = 144 KB scratch
    short* WkB = ws;
    short* WvB = ws + WKV_ELEMS;
    short* WqB = ws + 2 * WKV_ELEMS;
    short* WoB = ws + 2 * WKV_ELEMS + WQO_ELEMS;
    short* WfB = ws + 2 * WKV_ELEMS + 2 * WQO_ELEMS;

    int prep_total = 2 * WKV_ELEMS + 2 * WQO_ELEMS + WF_ELEMS;   // 73728 = 288 * 256
    hipLaunchKernelGGL(prep_kernel, dim3(prep_total / 256), dim3(256), 0, stream,
                       Wk, Wv, Wq, Wo, W_filt, ws);
    hipLaunchKernelGGL(tdt_main, dim3(BB * AA), dim3(256), 0, stream,
                       x, r_ij, f_ij, b_filt, bo, nbr, msk,
                       WkB, WvB, WqB, WoB, WfB, out);
}